// Round 1
// baseline (366.333 us; speedup 1.0000x reference)
//
#include <hip/hip_runtime.h>

#define N_NODES 10000
#define N_EDGES 640000
#define N_GRAPHS 64
#define FEATS 128

// ---------------------------------------------------------------------------
// small utility
static inline size_t align_up(size_t x, size_t a) { return (x + a - 1) & ~(a - 1); }

// ---------------------------------------------------------------------------
// 1) degree histograms over edges
__global__ __launch_bounds__(256) void degree_kernel(const int* __restrict__ src,
                                                     const int* __restrict__ dst,
                                                     int* __restrict__ deg_out,
                                                     int* __restrict__ deg_in) {
    int e = blockIdx.x * 256 + threadIdx.x;
    if (e < N_EDGES) {
        atomicAdd(&deg_out[src[e]], 1);
        atomicAdd(&deg_in[dst[e]], 1);
    }
}

// ---------------------------------------------------------------------------
// 2) exclusive scan of deg_in -> offsets[N_NODES+1], single block of 1024
__global__ __launch_bounds__(1024) void scan_kernel(const int* __restrict__ deg_in,
                                                    int* __restrict__ offsets) {
    __shared__ int part[1024];
    const int PER = 10; // 1024*10 = 10240 >= 10000
    int tid = threadIdx.x;
    int base = tid * PER;
    int local[PER];
    int s = 0;
    for (int i = 0; i < PER; i++) {
        int idx = base + i;
        int v = (idx < N_NODES) ? deg_in[idx] : 0;
        local[i] = s;
        s += v;
    }
    part[tid] = s;
    __syncthreads();
    for (int off = 1; off < 1024; off <<= 1) {
        int v = 0;
        if (tid >= off) v = part[tid - off];
        __syncthreads();
        part[tid] += v;
        __syncthreads();
    }
    int blockOff = (tid > 0) ? part[tid - 1] : 0;
    for (int i = 0; i < PER; i++) {
        int idx = base + i;
        if (idx < N_NODES) offsets[idx] = blockOff + local[i];
    }
    if (tid == 1023) offsets[N_NODES] = part[1023];
}

// ---------------------------------------------------------------------------
// 3) per-node norms + graph count histogram
__global__ __launch_bounds__(256) void norm_kernel(const int* __restrict__ deg_out,
                                                   const int* __restrict__ deg_in,
                                                   const int* __restrict__ gids,
                                                   float* __restrict__ norm_src,
                                                   float* __restrict__ norm_dst,
                                                   int* __restrict__ graph_cnt) {
    int n = blockIdx.x * 256 + threadIdx.x;
    if (n < N_NODES) {
        int dout = deg_out[n]; if (dout < 1) dout = 1;
        int din  = deg_in[n];  if (din  < 1) din  = 1;
        norm_src[n] = rsqrtf((float)dout);
        norm_dst[n] = rsqrtf((float)din);
        atomicAdd(&graph_cnt[gids[n]], 1);
    }
}

// ---------------------------------------------------------------------------
// 4) counting-sort scatter: edges sorted by dst (CSR), store src id
__global__ __launch_bounds__(256) void scatter_kernel(const int* __restrict__ src,
                                                      const int* __restrict__ dst,
                                                      const int* __restrict__ offsets,
                                                      int* __restrict__ cursor,
                                                      int* __restrict__ sorted_src) {
    int e = blockIdx.x * 256 + threadIdx.x;
    if (e < N_EDGES) {
        int d = dst[e];
        int pos = offsets[d] + atomicAdd(&cursor[d], 1);
        sorted_src[pos] = src[e];
    }
}

// ---------------------------------------------------------------------------
// 5) xs = in_feat * norm_src  (float4 elementwise)
__global__ __launch_bounds__(256) void prescale_kernel(const float* __restrict__ in_feat,
                                                       const float* __restrict__ norm_src,
                                                       float* __restrict__ xs) {
    int i = blockIdx.x * 256 + threadIdx.x; // over N_NODES*FEATS/4 = 320000
    if (i < N_NODES * (FEATS / 4)) {
        int n = i >> 5; // 32 float4 per node
        float4 v = ((const float4*)in_feat)[i];
        float s = norm_src[n];
        v.x *= s; v.y *= s; v.z *= s; v.w *= s;
        ((float4*)xs)[i] = v;
    }
}

// ---------------------------------------------------------------------------
// 6) aggregation: one block (128 threads) per dst node; atomic-free
__global__ __launch_bounds__(128) void aggregate_kernel(const float* __restrict__ xs,
                                                        const int* __restrict__ sorted_src,
                                                        const int* __restrict__ offsets,
                                                        const float* __restrict__ norm_dst,
                                                        float* __restrict__ agg) {
    int n = blockIdx.x;
    int t = threadIdx.x;
    int start = offsets[n];
    int end   = offsets[n + 1];
    float acc = 0.f;
    int e = start;
    for (; e + 4 <= end; e += 4) {
        int s0 = sorted_src[e + 0];
        int s1 = sorted_src[e + 1];
        int s2 = sorted_src[e + 2];
        int s3 = sorted_src[e + 3];
        float v0 = xs[s0 * FEATS + t];
        float v1 = xs[s1 * FEATS + t];
        float v2 = xs[s2 * FEATS + t];
        float v3 = xs[s3 * FEATS + t];
        acc += v0 + v1 + v2 + v3;
    }
    for (; e < end; e++) acc += xs[sorted_src[e] * FEATS + t];
    agg[n * FEATS + t] = acc * norm_dst[n];
}

// ---------------------------------------------------------------------------
// 7) GEMM1: out = relu(A @ W + b) * scale   (16 nodes x 128 feats per block)
__global__ __launch_bounds__(256) void gemm_relu_scale_kernel(const float* __restrict__ A,
                                                              const float* __restrict__ W,
                                                              const float* __restrict__ bias,
                                                              const float* __restrict__ scale,
                                                              float* __restrict__ out) {
    __shared__ float As[16 * FEATS];
    int tid = threadIdx.x;
    int nb = blockIdx.x * 16;
    const float4* av = (const float4*)(A + (size_t)nb * FEATS);
    float4* sv = (float4*)As;
    sv[tid]       = av[tid];
    sv[tid + 256] = av[tid + 256];
    __syncthreads();
    int fg = (tid & 31) << 2; // feature group start
    int r  = tid >> 5;        // 0..7
    const float* a0p = As + r * FEATS;
    const float* a1p = As + (r + 8) * FEATS;
    float4 acc0 = make_float4(0.f, 0.f, 0.f, 0.f);
    float4 acc1 = make_float4(0.f, 0.f, 0.f, 0.f);
#pragma unroll 4
    for (int k = 0; k < FEATS; k++) {
        float a0 = a0p[k];
        float a1 = a1p[k];
        float4 w = *(const float4*)(W + k * FEATS + fg);
        acc0.x = fmaf(a0, w.x, acc0.x);
        acc0.y = fmaf(a0, w.y, acc0.y);
        acc0.z = fmaf(a0, w.z, acc0.z);
        acc0.w = fmaf(a0, w.w, acc0.w);
        acc1.x = fmaf(a1, w.x, acc1.x);
        acc1.y = fmaf(a1, w.y, acc1.y);
        acc1.z = fmaf(a1, w.z, acc1.z);
        acc1.w = fmaf(a1, w.w, acc1.w);
    }
    float4 bb = *(const float4*)(bias + fg);
    int gn0 = nb + r, gn1 = nb + r + 8;
    float s0 = scale[gn0], s1 = scale[gn1];
    float4 o0, o1;
    o0.x = fmaxf(acc0.x + bb.x, 0.f) * s0;
    o0.y = fmaxf(acc0.y + bb.y, 0.f) * s0;
    o0.z = fmaxf(acc0.z + bb.z, 0.f) * s0;
    o0.w = fmaxf(acc0.w + bb.w, 0.f) * s0;
    o1.x = fmaxf(acc1.x + bb.x, 0.f) * s1;
    o1.y = fmaxf(acc1.y + bb.y, 0.f) * s1;
    o1.z = fmaxf(acc1.z + bb.z, 0.f) * s1;
    o1.w = fmaxf(acc1.w + bb.w, 0.f) * s1;
    *(float4*)(out + (size_t)gn0 * FEATS + fg) = o0;
    *(float4*)(out + (size_t)gn1 * FEATS + fg) = o1;
}

// ---------------------------------------------------------------------------
// 8) GEMM2 fused with head: per node s = relu(A@W2+b2) . Wd ; atomicAdd into
//    graph_sum[graph_id[node]]  (h2 never materialized)
__global__ __launch_bounds__(256) void gemm_relu_pool_kernel(const float* __restrict__ A,
                                                             const float* __restrict__ W,
                                                             const float* __restrict__ bias,
                                                             const float* __restrict__ Wd,
                                                             const int* __restrict__ gids,
                                                             float* __restrict__ graph_sum) {
    __shared__ float As[16 * FEATS];
    int tid = threadIdx.x;
    int nb = blockIdx.x * 16;
    const float4* av = (const float4*)(A + (size_t)nb * FEATS);
    float4* sv = (float4*)As;
    sv[tid]       = av[tid];
    sv[tid + 256] = av[tid + 256];
    __syncthreads();
    int fg = (tid & 31) << 2;
    int r  = tid >> 5;
    const float* a0p = As + r * FEATS;
    const float* a1p = As + (r + 8) * FEATS;
    float4 acc0 = make_float4(0.f, 0.f, 0.f, 0.f);
    float4 acc1 = make_float4(0.f, 0.f, 0.f, 0.f);
#pragma unroll 4
    for (int k = 0; k < FEATS; k++) {
        float a0 = a0p[k];
        float a1 = a1p[k];
        float4 w = *(const float4*)(W + k * FEATS + fg);
        acc0.x = fmaf(a0, w.x, acc0.x);
        acc0.y = fmaf(a0, w.y, acc0.y);
        acc0.z = fmaf(a0, w.z, acc0.z);
        acc0.w = fmaf(a0, w.w, acc0.w);
        acc1.x = fmaf(a1, w.x, acc1.x);
        acc1.y = fmaf(a1, w.y, acc1.y);
        acc1.z = fmaf(a1, w.z, acc1.z);
        acc1.w = fmaf(a1, w.w, acc1.w);
    }
    float4 bb = *(const float4*)(bias + fg);
    float4 wd = *(const float4*)(Wd + fg);
    float p0 = fmaxf(acc0.x + bb.x, 0.f) * wd.x + fmaxf(acc0.y + bb.y, 0.f) * wd.y +
               fmaxf(acc0.z + bb.z, 0.f) * wd.z + fmaxf(acc0.w + bb.w, 0.f) * wd.w;
    float p1 = fmaxf(acc1.x + bb.x, 0.f) * wd.x + fmaxf(acc1.y + bb.y, 0.f) * wd.y +
               fmaxf(acc1.z + bb.z, 0.f) * wd.z + fmaxf(acc1.w + bb.w, 0.f) * wd.w;
    // reduce across the 32 lanes of each half-wave row-group
#pragma unroll
    for (int d = 16; d >= 1; d >>= 1) {
        p0 += __shfl_down(p0, d);
        p1 += __shfl_down(p1, d);
    }
    if ((tid & 31) == 0) {
        int gn0 = nb + r, gn1 = nb + r + 8;
        atomicAdd(&graph_sum[gids[gn0]], p0);
        atomicAdd(&graph_sum[gids[gn1]], p1);
    }
}

// ---------------------------------------------------------------------------
// 9) final: out[g] = graph_sum[g] / max(cnt,1) + bd
__global__ __launch_bounds__(64) void final_kernel(const float* __restrict__ graph_sum,
                                                   const int* __restrict__ graph_cnt,
                                                   const float* __restrict__ bd,
                                                   float* __restrict__ out) {
    int g = threadIdx.x;
    if (g < N_GRAPHS) {
        out[g] = graph_sum[g] / fmaxf((float)graph_cnt[g], 1.f) + bd[0];
    }
}

// ---------------------------------------------------------------------------
extern "C" void kernel_launch(void* const* d_in, const int* in_sizes, int n_in,
                              void* d_out, int out_size, void* d_ws, size_t ws_size,
                              hipStream_t stream) {
    const float* in_feat = (const float*)d_in[0];
    const int*   src     = (const int*)d_in[1];
    const int*   dst     = (const int*)d_in[2];
    const int*   gids    = (const int*)d_in[3];
    const float* W1      = (const float*)d_in[4];
    const float* b1      = (const float*)d_in[5];
    const float* W2      = (const float*)d_in[6];
    const float* b2      = (const float*)d_in[7];
    const float* Wd      = (const float*)d_in[8];
    const float* bd      = (const float*)d_in[9];
    float* out = (float*)d_out;

    char* ws = (char*)d_ws;
    size_t off = 0;
    // --- zero zone (one memset covers all) ---
    int* deg_out = (int*)(ws + off); off += N_NODES * 4;                 // 40000
    int* deg_in  = (int*)(ws + off); off += N_NODES * 4;                 // 80000
    int* cursor  = (int*)(ws + off); off += N_NODES * 4;                 // 120000
    int* graph_cnt = (int*)(ws + off); off += N_GRAPHS * 4;              // 120256
    float* graph_sum = (float*)(ws + off); off += N_GRAPHS * 4;          // 120512
    size_t zero_bytes = off;
    // --- non-zeroed scratch ---
    off = align_up(off, 512);
    int* offsets = (int*)(ws + off); off += (N_NODES + 1) * 4;
    off = align_up(off, 512);
    float* norm_src = (float*)(ws + off); off += N_NODES * 4;
    off = align_up(off, 512);
    float* norm_dst = (float*)(ws + off); off += N_NODES * 4;
    off = align_up(off, 512);
    int* sorted_src = (int*)(ws + off); off += (size_t)N_EDGES * 4;
    off = align_up(off, 512);
    float* xs  = (float*)(ws + off); off += (size_t)N_NODES * FEATS * 4;
    off = align_up(off, 512);
    float* agg = (float*)(ws + off); off += (size_t)N_NODES * FEATS * 4;
    (void)ws_size; // ~13 MB used

    hipMemsetAsync(ws, 0, zero_bytes, stream);

    const int EDGE_BLOCKS = (N_EDGES + 255) / 256;   // 2500
    const int NODE_BLOCKS = (N_NODES + 255) / 256;   // 40

    degree_kernel<<<EDGE_BLOCKS, 256, 0, stream>>>(src, dst, deg_out, deg_in);
    scan_kernel<<<1, 1024, 0, stream>>>(deg_in, offsets);
    norm_kernel<<<NODE_BLOCKS, 256, 0, stream>>>(deg_out, deg_in, gids, norm_src, norm_dst, graph_cnt);
    scatter_kernel<<<EDGE_BLOCKS, 256, 0, stream>>>(src, dst, offsets, cursor, sorted_src);
    prescale_kernel<<<(N_NODES * (FEATS / 4) + 255) / 256, 256, 0, stream>>>(in_feat, norm_src, xs);

    // layer 1
    aggregate_kernel<<<N_NODES, 128, 0, stream>>>(xs, sorted_src, offsets, norm_dst, agg);
    gemm_relu_scale_kernel<<<N_NODES / 16, 256, 0, stream>>>(agg, W1, b1, norm_src, xs);

    // layer 2 (+ fused pool/head)
    aggregate_kernel<<<N_NODES, 128, 0, stream>>>(xs, sorted_src, offsets, norm_dst, agg);
    gemm_relu_pool_kernel<<<N_NODES / 16, 256, 0, stream>>>(agg, W2, b2, Wd, gids, graph_sum);

    final_kernel<<<1, 64, 0, stream>>>(graph_sum, graph_cnt, bd, out);
}